// Round 1
// baseline (353.538 us; speedup 1.0000x reference)
//
#include <hip/hip_runtime.h>
#include <hip/hip_bf16.h>
#include <stdint.h>

// ---- problem constants ----
#define B64   64
#define DIMS  120
#define NLOC  (DIMS*DIMS)      // 14400 V1 locations
#define V4D   29
#define NLOC4 (V4D*V4D)        // 841 V4 locations

typedef __attribute__((ext_vector_type(8))) short bf16x8;  // 8 bf16 in 4 VGPRs
typedef __attribute__((ext_vector_type(4))) float f32x4;

__device__ __forceinline__ unsigned short f2bf(float f) {
    unsigned u = __float_as_uint(f);
    u += 0x7fffu + ((u >> 16) & 1u);   // round-to-nearest-even
    return (unsigned short)(u >> 16);
}

// async global->LDS, 16B per lane (DMA; no VALU, no VGPR round-trip)
__device__ __forceinline__ void gload16(const float* g, float* l) {
    __builtin_amdgcn_global_load_lds(
        (const __attribute__((address_space(1))) unsigned int*)g,
        (__attribute__((address_space(3))) unsigned int*)l, 16, 0, 0);
}

// ------------------------------------------------------------------
// k0: pack x into two bf16 replica tensors with b innermost for coalesced
// MFMA A-fragment loads (16 lanes x 16B = 256B contiguous per quarter):
//   xrep [r][col][g][b][q]  = x[b][8g+r+q][col]   (rows chunked)
//   xrepT[rc][row][gc][b][q] = x[b][row][8gc+rc+q] (cols chunked)
// Also bias-initializes out[64][2] (block 0) for k2's fused atomic readout.
// ------------------------------------------------------------------
__global__ __launch_bounds__(256) void k0_pack(const float* __restrict__ x,
                                               unsigned short* __restrict__ xrep,
                                               unsigned short* __restrict__ xrepT,
                                               const float* __restrict__ db,
                                               float* __restrict__ out) {
    __shared__ unsigned short tile[16 * 16 * 64];   // [d1][d2][b]
    int blk = blockIdx.x;
    int tid = threadIdx.x;
    if (blk == 0 && tid < 128) out[tid] = db[tid & 1];   // out[b][cls] = bias
    int isT = (blk >= 128) ? 1 : 0;
    int b2 = blk - 128 * isT;
    int g = b2 >> 3;             // chunk index 0..15
    int fb = (b2 & 7) << 4;      // fixed-dim block base
    int bb = tid >> 2, c4 = (tid & 3) << 2;
#pragma unroll 4
    for (int rr = 0; rr < 16; ++rr) {
        int row, col;
        if (!isT) { row = 8 * g + rr; col = fb + c4; }
        else      { row = fb + rr;    col = 8 * g + c4; }
        f32x4 v;
        if (row < 128 && col < 128)
            v = *(const f32x4*)(x + ((size_t)bb * 128 + row) * 128 + col);
        else
            v = (f32x4){0.f, 0.f, 0.f, 0.f};
#pragma unroll
        for (int cc = 0; cc < 4; ++cc) {
            int d1 = isT ? rr : (c4 + cc);
            int d2 = isT ? (c4 + cc) : rr;
            tile[(d1 * 16 + d2) * 64 + bb] = f2bf(v[cc]);
        }
    }
    __syncthreads();
    unsigned short* outp = isT ? xrepT : xrep;
    int b = tid & 63;
#pragma unroll
    for (int it = 0; it < 32; ++it) {
        int u = (it * 256 + tid) >> 6;   // 0..127
        int d1 = u & 15, rq = u >> 4;    // rq = r (or rc), 0..7
        bf16x8 pk;
#pragma unroll
        for (int q = 0; q < 8; ++q)
            pk[q] = (short)tile[(d1 * 16 + rq + q) * 64 + b];
        size_t off = ((((size_t)rq * 128 + (fb + d1)) * 16 + g) * 64 + b) * 8;
        *(bf16x8*)(outp + off) = pk;
    }
}

// ------------------------------------------------------------------
// k1: V1 locally-connected + relu + phase-mean. One wave per location,
// 4 consecutive locations per block. K = 96 (3 MFMA K-steps),
// chunk ch = ks*4 + t:
//   ch 0..8 : patch col kw=ch, rows i..i+7   -> xrep  (e = jj*9+ch)
//   ch 9    : row i+8, cols j..j+7           -> xrepT (e = 72+jj)
//   ch 10   : row i+8, col j+8 (jj==0 only)  -> xrepT at gc+1 (e = 80)
//   ch 11   : pad (masked to zero)
// Weights staged RAW fp32 via global_load_lds DMA: stage[c][loc4][81]
// (1296B per c, contiguous & 16B-aligned in sw). Zero staging VALU/LDS-ops.
// B-frags assembled read-side: 8 ds_read_b32 (stride 36B) + f2bf.
// ------------------------------------------------------------------
__global__ __launch_bounds__(256) void k1_v1(const unsigned short* __restrict__ xrep,
                                             const unsigned short* __restrict__ xrepT,
                                             const float* __restrict__ sw,
                                             unsigned short* __restrict__ cplx) {
    __shared__ __align__(16) char smraw[41472];     // 32c * 324 f32
    float* stagef = (float*)smraw;                   // [c][w][81] fp32
    float* pool2 = (float*)smraw;                    // [w][64][9] fp32 (overlay, post-barrier)

    int tid = threadIdx.x;
    int blk = blockIdx.x;
    int blk2 = (blk & 7) * 450 + (blk >> 3);   // XCD band swizzle (3600 = 8*450)
    int loc0 = blk2 * 4;

    int w = tid >> 6, l = tid & 63;

    // ---- stage sw for 4 locations via global->LDS DMA (wave w: c = 8w..8w+7)
#pragma unroll
    for (int cc = 0; cc < 8; ++cc) {
        int c = w * 8 + cc;
        const float* g = sw + ((size_t)c * NLOC + loc0) * 81;   // 1296B, 16B-aligned
        float* lp = stagef + c * 324;
        gload16(g + l * 4, lp + l * 4);                          // bytes 0..1023
        if (l < 17)
            gload16(g + 256 + l * 4, lp + 256 + l * 4);          // bytes 1024..1295
    }

    int loc = loc0 + w;
    int i = loc / DIMS, j = loc - i * DIMS;
    int ln = l & 15, t = l >> 4;
    int r = i & 7, g2 = i >> 3, rc = j & 7, gc = j >> 3;

    // per-lane B read bases (two n-tiles), fp32 rows
    const float* bb0 = stagef + (size_t)ln * 324 + w * 81;
    const float* bb1 = bb0 + 16 * 324;
    // ks=2 per-lane pattern: off/stride in dwords
    int off2 = (t == 0) ? 8 : ((t == 1) ? 72 : 80);
    int strd2 = (t == 0) ? 9 : ((t == 1) ? 1 : 0);
    bool keep0 = (t <= 2);   // jj==0 valid unless t==3
    bool keepR = (t <= 1);   // jj>=1 valid only for t<=1

    f32x4 acc[4][2];
#pragma unroll
    for (int mt = 0; mt < 4; ++mt)
#pragma unroll
        for (int nt = 0; nt < 2; ++nt)
            acc[mt][nt] = (f32x4){0.f, 0.f, 0.f, 0.f};

    __syncthreads();   // drain DMA (compiler emits vmcnt(0) before barrier)

#pragma unroll
    for (int ks = 0; ks < 3; ++ks) {
        int ch = ks * 4 + t;
        // ---- A fragments (coalesced 16B global loads) ----
        const unsigned short* abase;
        if (ks < 2) {
            int col = j + ch;    // ch <= 7 here
            abase = xrep + (((size_t)r * 128 + col) * 16 + g2) * 512;
        } else {
            const unsigned short* a0 = xrep + (((size_t)r * 128 + (j + 8)) * 16 + g2) * 512;
            int gc2 = gc + ((t >= 2) ? 1 : 0);
            const unsigned short* a1 = xrepT + (((size_t)rc * 128 + (i + 8)) * 16 + gc2) * 512;
            abase = (t == 0) ? a0 : a1;
        }
        bf16x8 a[4];
#pragma unroll
        for (int mt = 0; mt < 4; ++mt)
            a[mt] = *(const bf16x8*)(abase + (size_t)(ln + 16 * mt) * 8);
        // ---- B fragments: 8 ds_read_b32 + f2bf each ----
        bf16x8 bfr[2];
        if (ks < 2) {
#pragma unroll
            for (int jj = 0; jj < 8; ++jj) {
                bfr[0][jj] = (short)f2bf(bb0[ch + jj * 9]);
                bfr[1][jj] = (short)f2bf(bb1[ch + jj * 9]);
            }
        } else {
            {
                float v0 = bb0[off2], v1 = bb1[off2];
                bfr[0][0] = (short)f2bf(keep0 ? v0 : 0.0f);
                bfr[1][0] = (short)f2bf(keep0 ? v1 : 0.0f);
            }
            int o = off2;
#pragma unroll
            for (int jj = 1; jj < 8; ++jj) {
                o += strd2;
                float v0 = bb0[o], v1 = bb1[o];
                bfr[0][jj] = (short)f2bf(keepR ? v0 : 0.0f);
                bfr[1][jj] = (short)f2bf(keepR ? v1 : 0.0f);
            }
        }
        // ---- MFMAs ----
#pragma unroll
        for (int mt = 0; mt < 4; ++mt)
#pragma unroll
            for (int nt = 0; nt < 2; ++nt)
                acc[mt][nt] = __builtin_amdgcn_mfma_f32_16x16x32_bf16(
                    a[mt], bfr[nt], acc[mt][nt], 0, 0, 0);
    }

    // ---- epilogue: relu, phase-mean via shfl_xor, LDS transpose, store ----
    __syncthreads();                     // stage dead only after ALL waves done
    float* pl = pool2 + w * 64 * 9;
#pragma unroll
    for (int mt = 0; mt < 4; ++mt)
#pragma unroll
        for (int nt = 0; nt < 2; ++nt)
#pragma unroll
            for (int reg = 0; reg < 4; ++reg) {
                float v = fmaxf(acc[mt][nt][reg], 0.0f);
                v += __shfl_xor(v, 1, 64);
                v += __shfl_xor(v, 2, 64);
                if ((ln & 3) == 0) {
                    int b = 16 * mt + 4 * t + reg;
                    int s = 4 * nt + (ln >> 2);
                    pl[b * 9 + s] = v * 0.25f;
                }
            }
    __syncthreads();
    bf16x8 po;
#pragma unroll
    for (int s = 0; s < 8; ++s)
        po[s] = (short)f2bf(pl[l * 9 + s]);
    *(bf16x8*)(cplx + (size_t)loc * 512 + l * 8) = po;
}

// ------------------------------------------------------------------
// k2: V4 pooling + FUSED decision readout. One block per location; vw
// slice staged RAW fp32 via global_load_lds DMA: row ro=o*8+s (256B,
// 256B-aligned) -> LDS base (s*16+o)*68 dwords (272B stride: 16B-aligned
// bases, 2-way banks). B-frag read-side: 8 ds_read_b32 + f2bf.
// 4 waves split K, LDS reduce across waves; then each (b,o) value is
// multiplied by dw[cls][o*841+loc], reduced over o via 16-lane shfl_xor,
// and atomically accumulated into out[b][cls] (bias pre-set by k0).
// Eliminates the v4s intermediate (6.9 MB RW) and the k3 launch.
// ------------------------------------------------------------------
__global__ __launch_bounds__(256) void k2_v4(const unsigned short* __restrict__ cplx,
                                             const float* __restrict__ vw,
                                             const float* __restrict__ dw,
                                             float* __restrict__ out) {
    __shared__ __align__(16) char smraw[128 * 68 * 4];   // 34816 B
    float* stg = (float*)smraw;                          // [s*16+o][68] fp32
    float* pool = (float*)smraw;                         // [4][64][16] fp32 (overlay)

    int tid = threadIdx.x;
    int blk = blockIdx.x;
    int loc = (blk < 840) ? ((blk & 7) * 105 + (blk >> 3)) : 840;  // XCD band swizzle
    int oi = loc / V4D, oj = loc - oi * V4D;

    int w = tid >> 6, l = tid & 63;

    // ---- stage vw[.,.,loc,.] via DMA: wave w rows ro = 32w..32w+31 ----
    if (l < 16) {
#pragma unroll
        for (int m = 0; m < 32; ++m) {
            int ro = w * 32 + m;
            int o = ro >> 3, s = ro & 7;
            const float* g = vw + ((size_t)ro * NLOC4 + loc) * 64;   // 256B aligned
            float* lp = stg + (s * 16 + o) * 68;
            gload16(g + l * 4, lp + l * 4);
        }
    }

    int ln = l & 15, t = l >> 4;
    f32x4 acc[4];
#pragma unroll
    for (int mt = 0; mt < 4; ++mt) acc[mt] = (f32x4){0.f, 0.f, 0.f, 0.f};

    __syncthreads();   // drain DMA

    const float* brow = stg + ln * 68;
#pragma unroll
    for (int kk = 0; kk < 4; ++kk) {
        int pos = 4 * (w * 4 + kk) + t;      // 0..63
        int kh = pos >> 3, kw = pos & 7;
        int iloc = (oi * 4 + kh) * DIMS + oj * 4 + kw;
        const unsigned short* ab = cplx + (size_t)iloc * 512 + ln * 8;
        bf16x8 a[4];
#pragma unroll
        for (int mt = 0; mt < 4; ++mt)
            a[mt] = *(const bf16x8*)(ab + mt * 128);
        bf16x8 bb;
#pragma unroll
        for (int s = 0; s < 8; ++s)
            bb[s] = (short)f2bf(brow[s * 16 * 68 + pos]);
#pragma unroll
        for (int mt = 0; mt < 4; ++mt)
            acc[mt] = __builtin_amdgcn_mfma_f32_16x16x32_bf16(a[mt], bb, acc[mt], 0, 0, 0);
    }
    __syncthreads();                       // stg dead; pool overlays
#pragma unroll
    for (int mt = 0; mt < 4; ++mt)
#pragma unroll
        for (int reg = 0; reg < 4; ++reg)
            pool[((w * 64) + 16 * mt + 4 * t + reg) * 16 + ln] = acc[mt][reg];
    __syncthreads();
    // ---- fused decision readout ----
    int o = tid & 15, brw = tid >> 4;
    const float* dw0 = dw + (size_t)o * NLOC4 + loc;     // dw[0][o][loc]
    float w0 = dw0[0];
    float w1 = dw0[16 * NLOC4];                           // dw[1][o][loc]
#pragma unroll
    for (int itb = 0; itb < 4; ++itb) {
        int b = brw + 16 * itb;
        float s = pool[(0 * 64 + b) * 16 + o] + pool[(1 * 64 + b) * 16 + o] +
                  pool[(2 * 64 + b) * 16 + o] + pool[(3 * 64 + b) * 16 + o];
        float c0 = s * w0;
        float c1 = s * w1;
        // reduce over the 16 o-lanes (xor masks <16 stay inside the group)
        c0 += __shfl_xor(c0, 1, 64);  c1 += __shfl_xor(c1, 1, 64);
        c0 += __shfl_xor(c0, 2, 64);  c1 += __shfl_xor(c1, 2, 64);
        c0 += __shfl_xor(c0, 4, 64);  c1 += __shfl_xor(c1, 4, 64);
        c0 += __shfl_xor(c0, 8, 64);  c1 += __shfl_xor(c1, 8, 64);
        if (o == 0) {
            atomicAdd(out + 2 * b + 0, c0);
            atomicAdd(out + 2 * b + 1, c1);
        }
    }
}

// ------------------------------------------------------------------
extern "C" void kernel_launch(void* const* d_in, const int* in_sizes, int n_in,
                              void* d_out, int out_size, void* d_ws, size_t ws_size,
                              hipStream_t stream) {
    const float* x  = (const float*)d_in[0];   // [64][1][128][128]
    const float* sw = (const float*)d_in[1];   // [32][120][120][81]
    const float* vw = (const float*)d_in[2];   // [16][8][29][29][64]
    const float* dw = (const float*)d_in[3];   // [2][13456]
    const float* db = (const float*)d_in[4];   // [2]
    float* out = (float*)d_out;                // [64][2]

    char* ws = (char*)d_ws;
    unsigned short* xrep  = (unsigned short*)ws;                         // 16,777,216 B
    unsigned short* xrepT = (unsigned short*)(ws + 16777216);            // 16,777,216 B
    unsigned short* cplx  = (unsigned short*)(ws + 33554432);            // 14,745,600 B

    k0_pack<<<256, 256, 0, stream>>>(x, xrep, xrepT, db, out);
    k1_v1<<<NLOC / 4, 256, 0, stream>>>(xrep, xrepT, sw, cplx);
    k2_v4<<<NLOC4, 256, 0, stream>>>(cplx, vw, dw, out);
}

// Round 3
// 278.860 us; speedup vs baseline: 1.2678x; 1.2678x over previous
//
#include <hip/hip_runtime.h>
#include <hip/hip_bf16.h>
#include <stdint.h>

// ---- problem constants ----
#define B64   64
#define DIMS  120
#define NLOC  (DIMS*DIMS)      // 14400 V1 locations
#define V4D   29
#define NLOC4 (V4D*V4D)        // 841 V4 locations

typedef __attribute__((ext_vector_type(8))) short bf16x8;  // 8 bf16 in 4 VGPRs
typedef __attribute__((ext_vector_type(4))) short bf16x4;  // 4 bf16 in 2 VGPRs
typedef __attribute__((ext_vector_type(4))) float f32x4;

__device__ __forceinline__ unsigned short f2bf(float f) {
    unsigned u = __float_as_uint(f);
    u += 0x7fffu + ((u >> 16) & 1u);   // round-to-nearest-even
    return (unsigned short)(u >> 16);
}

// async global->LDS, 16B per lane (DMA; no VALU, no VGPR round-trip)
__device__ __forceinline__ void gload16(const float* g, float* l) {
    __builtin_amdgcn_global_load_lds(
        (const __attribute__((address_space(1))) unsigned int*)g,
        (__attribute__((address_space(3))) unsigned int*)l, 16, 0, 0);
}

// ------------------------------------------------------------------
// k0: pack x into two bf16 replica tensors with b innermost for coalesced
// MFMA A-fragment loads (16 lanes x 16B = 256B contiguous per quarter):
//   xrep [r][col][g][b][q]  = x[b][8g+r+q][col]   (rows chunked)
//   xrepT[rc][row][gc][b][q] = x[b][row][8gc+rc+q] (cols chunked)
// ------------------------------------------------------------------
__global__ __launch_bounds__(256) void k0_pack(const float* __restrict__ x,
                                               unsigned short* __restrict__ xrep,
                                               unsigned short* __restrict__ xrepT) {
    __shared__ unsigned short tile[16 * 16 * 64];   // [d1][d2][b]
    int blk = blockIdx.x;
    int isT = (blk >= 128) ? 1 : 0;
    int b2 = blk - 128 * isT;
    int g = b2 >> 3;             // chunk index 0..15
    int fb = (b2 & 7) << 4;      // fixed-dim block base
    int tid = threadIdx.x;
    int bb = tid >> 2, c4 = (tid & 3) << 2;
#pragma unroll 4
    for (int rr = 0; rr < 16; ++rr) {
        int row, col;
        if (!isT) { row = 8 * g + rr; col = fb + c4; }
        else      { row = fb + rr;    col = 8 * g + c4; }
        f32x4 v;
        if (row < 128 && col < 128)
            v = *(const f32x4*)(x + ((size_t)bb * 128 + row) * 128 + col);
        else
            v = (f32x4){0.f, 0.f, 0.f, 0.f};
#pragma unroll
        for (int cc = 0; cc < 4; ++cc) {
            int d1 = isT ? rr : (c4 + cc);
            int d2 = isT ? (c4 + cc) : rr;
            tile[(d1 * 16 + d2) * 64 + bb] = f2bf(v[cc]);
        }
    }
    __syncthreads();
    unsigned short* outp = isT ? xrepT : xrep;
    int b = tid & 63;
#pragma unroll
    for (int it = 0; it < 32; ++it) {
        int u = (it * 256 + tid) >> 6;   // 0..127
        int d1 = u & 15, rq = u >> 4;    // rq = r (or rc), 0..7
        bf16x8 pk;
#pragma unroll
        for (int q = 0; q < 8; ++q)
            pk[q] = (short)tile[(d1 * 16 + rq + q) * 64 + b];
        size_t off = ((((size_t)rq * 128 + (fb + d1)) * 16 + g) * 64 + b) * 8;
        *(bf16x8*)(outp + off) = pk;
    }
}

// ------------------------------------------------------------------
// k1: V1 locally-connected + relu + phase-mean.
// GRID-SPLIT over channels: 7200 blocks; half = blk&1 selects channels
// half*16..half*16+15; blk0 = blk>>1 selects 4 locations (one per wave).
// Every LDS address staged EXACTLY ONCE via global_load_lds DMA (same
// discipline as the proven monolithic kernel; no restage, no overlay).
// LDS: 20736 B stage + 5120 B pool = 25856 B -> 6 blocks/CU (24 waves/CU
// vs 12 before): 2x DMA latency-hiding depth.
// K = 96 (3 MFMA K-steps), chunk ch = ks*4 + t:
//   ch 0..8 : patch col kw=ch, rows i..i+7   -> xrep  (e = jj*9+ch)
//   ch 9    : row i+8, cols j..j+7           -> xrepT (e = 72+jj)
//   ch 10   : row i+8, col j+8 (jj==0 only)  -> xrepT at gc+1 (e = 80)
//   ch 11   : pad (masked to zero)
// Each block stores the 4-orientation half of each cplx row (8B/lane,
// disjoint halves of each 16B granule; ordered by kernel boundary).
// ------------------------------------------------------------------
__global__ __launch_bounds__(256) void k1_v1(const unsigned short* __restrict__ xrep,
                                             const unsigned short* __restrict__ xrepT,
                                             const float* __restrict__ sw,
                                             unsigned short* __restrict__ cplx) {
    __shared__ __align__(16) float stagef[16 * 324];   // 20736 B: [c16][loc4*81]
    __shared__ float pool2[4 * 64 * 5];                // 5120 B: [w][64][5]

    int tid = threadIdx.x;
    int blk = blockIdx.x;
    int half = blk & 1;                         // channel half: 0 -> c 0..15, 1 -> c 16..31
    int blk0 = blk >> 1;                        // location block 0..3599
    int blk2 = (blk0 & 7) * 450 + (blk0 >> 3);  // XCD band swizzle (3600 = 8*450)
    int loc0 = blk2 * 4;

    int w = tid >> 6, l = tid & 63;

    // ---- stage 16 channels via DMA: wave w stages c16 = 4w..4w+3 (ONCE) ----
#pragma unroll
    for (int cc = 0; cc < 4; ++cc) {
        int c16 = w * 4 + cc;
        int c = half * 16 + c16;
        const float* g = sw + ((size_t)c * NLOC + loc0) * 81;   // 1296B, 16B-aligned
        float* lp = stagef + c16 * 324;
        gload16(g + l * 4, lp + l * 4);                          // bytes 0..1023
        if (l < 17)
            gload16(g + 256 + l * 4, lp + 256 + l * 4);          // bytes 1024..1295
    }

    int loc = loc0 + w;
    int i = loc / DIMS, j = loc - i * DIMS;
    int ln = l & 15, t = l >> 4;
    int r = i & 7, g2 = i >> 3, rc = j & 7, gc = j >> 3;

    // per-lane B read base (slot ln = phase-local channel, location w)
    const float* bb0 = stagef + (size_t)ln * 324 + w * 81;
    // ks=2 per-lane pattern: off/stride in dwords
    int off2 = (t == 0) ? 8 : ((t == 1) ? 72 : 80);
    int strd2 = (t == 0) ? 9 : ((t == 1) ? 1 : 0);
    bool keep0 = (t <= 2);   // jj==0 valid unless t==3
    bool keepR = (t <= 1);   // jj>=1 valid only for t<=1

    f32x4 acc[4];
#pragma unroll
    for (int mt = 0; mt < 4; ++mt)
        acc[mt] = (f32x4){0.f, 0.f, 0.f, 0.f};

    __syncthreads();   // drain DMA (compiler emits vmcnt(0) before barrier)

#pragma unroll
    for (int ks = 0; ks < 3; ++ks) {
        int ch = ks * 4 + t;
        // ---- A fragments (coalesced 16B global loads) ----
        const unsigned short* abase;
        if (ks < 2) {
            int col = j + ch;    // ch <= 7 here
            abase = xrep + (((size_t)r * 128 + col) * 16 + g2) * 512;
        } else {
            const unsigned short* a0 = xrep + (((size_t)r * 128 + (j + 8)) * 16 + g2) * 512;
            int gc2 = gc + ((t >= 2) ? 1 : 0);
            const unsigned short* a1 = xrepT + (((size_t)rc * 128 + (i + 8)) * 16 + gc2) * 512;
            abase = (t == 0) ? a0 : a1;
        }
        bf16x8 a[4];
#pragma unroll
        for (int mt = 0; mt < 4; ++mt)
            a[mt] = *(const bf16x8*)(abase + (size_t)(ln + 16 * mt) * 8);
        // ---- B fragment: 8 ds_read_b32 + f2bf ----
        bf16x8 bfr;
        if (ks < 2) {
#pragma unroll
            for (int jj = 0; jj < 8; ++jj)
                bfr[jj] = (short)f2bf(bb0[ch + jj * 9]);
        } else {
            {
                float v0 = bb0[off2];
                bfr[0] = (short)f2bf(keep0 ? v0 : 0.0f);
            }
            int o = off2;
#pragma unroll
            for (int jj = 1; jj < 8; ++jj) {
                o += strd2;
                float v0 = bb0[o];
                bfr[jj] = (short)f2bf(keepR ? v0 : 0.0f);
            }
        }
        // ---- MFMAs ----
#pragma unroll
        for (int mt = 0; mt < 4; ++mt)
            acc[mt] = __builtin_amdgcn_mfma_f32_16x16x32_bf16(
                a[mt], bfr, acc[mt], 0, 0, 0);
    }

    // ---- epilogue: relu, phase-mean via shfl_xor, pool write ----
    float* pl = pool2 + w * 64 * 5;
#pragma unroll
    for (int mt = 0; mt < 4; ++mt)
#pragma unroll
        for (int reg = 0; reg < 4; ++reg) {
            float v = fmaxf(acc[mt][reg], 0.0f);
            v += __shfl_xor(v, 1, 64);
            v += __shfl_xor(v, 2, 64);
            if ((ln & 3) == 0) {
                int b = 16 * mt + 4 * t + reg;
                int s = ln >> 2;             // local orientation 0..3
                pl[b * 5 + s] = v * 0.25f;
            }
        }
    __syncthreads();   // pool writes visible before read-back

    // ---- pack & store 4 orientations (8B/lane, half-granule) ----
    bf16x4 po;
#pragma unroll
    for (int s = 0; s < 4; ++s)
        po[s] = (short)f2bf(pl[l * 5 + s]);
    *(bf16x4*)(cplx + (size_t)loc * 512 + l * 8 + half * 4) = po;
}

// ------------------------------------------------------------------
// k2: V4 pooling. One block per location; vw slice staged RAW fp32 via
// global_load_lds DMA: row ro=o*8+s (256B, 256B-aligned) -> LDS base
// (s*16+o)*68 dwords (272B stride: 16B-aligned bases, 2-way banks).
// B-frag read-side: 8 ds_read_b32 (imm offset s*4352B) + f2bf.
// 4 waves split K, LDS reduce across waves.
// ------------------------------------------------------------------
__global__ __launch_bounds__(256) void k2_v4(const unsigned short* __restrict__ cplx,
                                             const float* __restrict__ vw,
                                             float* __restrict__ v4s) {
    __shared__ __align__(16) char smraw[128 * 68 * 4];   // 34816 B
    float* stg = (float*)smraw;                          // [s*16+o][68] fp32
    float* pool = (float*)smraw;                         // [4][64][16] fp32 (overlay)

    int tid = threadIdx.x;
    int blk = blockIdx.x;
    int loc = (blk < 840) ? ((blk & 7) * 105 + (blk >> 3)) : 840;  // XCD band swizzle
    int oi = loc / V4D, oj = loc - oi * V4D;

    int w = tid >> 6, l = tid & 63;

    // ---- stage vw[.,.,loc,.] via DMA: wave w rows ro = 32w..32w+31 ----
    if (l < 16) {
#pragma unroll
        for (int m = 0; m < 32; ++m) {
            int ro = w * 32 + m;
            int o = ro >> 3, s = ro & 7;
            const float* g = vw + ((size_t)ro * NLOC4 + loc) * 64;   // 256B aligned
            float* lp = stg + (s * 16 + o) * 68;
            gload16(g + l * 4, lp + l * 4);
        }
    }

    int ln = l & 15, t = l >> 4;
    f32x4 acc[4];
#pragma unroll
    for (int mt = 0; mt < 4; ++mt) acc[mt] = (f32x4){0.f, 0.f, 0.f, 0.f};

    __syncthreads();   // drain DMA

    const float* brow = stg + ln * 68;
#pragma unroll
    for (int kk = 0; kk < 4; ++kk) {
        int pos = 4 * (w * 4 + kk) + t;      // 0..63
        int kh = pos >> 3, kw = pos & 7;
        int iloc = (oi * 4 + kh) * DIMS + oj * 4 + kw;
        const unsigned short* ab = cplx + (size_t)iloc * 512 + ln * 8;
        bf16x8 a[4];
#pragma unroll
        for (int mt = 0; mt < 4; ++mt)
            a[mt] = *(const bf16x8*)(ab + mt * 128);
        bf16x8 bb;
#pragma unroll
        for (int s = 0; s < 8; ++s)
            bb[s] = (short)f2bf(brow[s * 16 * 68 + pos]);
#pragma unroll
        for (int mt = 0; mt < 4; ++mt)
            acc[mt] = __builtin_amdgcn_mfma_f32_16x16x32_bf16(a[mt], bb, acc[mt], 0, 0, 0);
    }
    __syncthreads();                       // stg dead; pool overlays
#pragma unroll
    for (int mt = 0; mt < 4; ++mt)
#pragma unroll
        for (int reg = 0; reg < 4; ++reg)
            pool[((w * 64) + 16 * mt + 4 * t + reg) * 16 + ln] = acc[mt][reg];
    __syncthreads();
    int o = tid & 15, brw = tid >> 4;
#pragma unroll
    for (int itb = 0; itb < 4; ++itb) {
        int b = brw + 16 * itb;
        float s = pool[(0 * 64 + b) * 16 + o] + pool[(1 * 64 + b) * 16 + o] +
                  pool[(2 * 64 + b) * 16 + o] + pool[(3 * 64 + b) * 16 + o];
        v4s[(size_t)loc * 1024 + b * 16 + o] = s;
    }
}

// ------------------------------------------------------------------
// k3: decision readout. One block per batch element.
// ------------------------------------------------------------------
__global__ __launch_bounds__(256) void k3_dec(const float* __restrict__ v4s,
                                              const float* __restrict__ dw,
                                              const float* __restrict__ db,
                                              float* __restrict__ out) {
    int b = blockIdx.x, tid = threadIdx.x;
    float a0 = 0.f, a1 = 0.f;
    for (int loc = tid; loc < NLOC4; loc += 256) {
        const float* vp = v4s + (size_t)loc * 1024 + b * 16;
#pragma unroll
        for (int o4 = 0; o4 < 4; ++o4) {
            f32x4 v = *(const f32x4*)(vp + o4 * 4);
#pragma unroll
            for (int q = 0; q < 4; ++q) {
                int o = o4 * 4 + q;
                a0 += v[q] * dw[o * NLOC4 + loc];
                a1 += v[q] * dw[16 * NLOC4 + o * NLOC4 + loc];
            }
        }
    }
    __shared__ float r0[256], r1[256];
    r0[tid] = a0; r1[tid] = a1;
    __syncthreads();
    for (int s = 128; s > 0; s >>= 1) {
        if (tid < s) { r0[tid] += r0[tid + s]; r1[tid] += r1[tid + s]; }
        __syncthreads();
    }
    if (tid == 0) {
        out[2 * b + 0] = r0[0] + db[0];
        out[2 * b + 1] = r1[0] + db[1];
    }
}

// ------------------------------------------------------------------
extern "C" void kernel_launch(void* const* d_in, const int* in_sizes, int n_in,
                              void* d_out, int out_size, void* d_ws, size_t ws_size,
                              hipStream_t stream) {
    const float* x  = (const float*)d_in[0];   // [64][1][128][128]
    const float* sw = (const float*)d_in[1];   // [32][120][120][81]
    const float* vw = (const float*)d_in[2];   // [16][8][29][29][64]
    const float* dw = (const float*)d_in[3];   // [2][13456]
    const float* db = (const float*)d_in[4];   // [2]
    float* out = (float*)d_out;                // [64][2]

    char* ws = (char*)d_ws;
    unsigned short* xrep  = (unsigned short*)ws;                         // 16,777,216 B
    unsigned short* xrepT = (unsigned short*)(ws + 16777216);            // 16,777,216 B
    unsigned short* cplx  = (unsigned short*)(ws + 33554432);            // 14,745,600 B
    float*          v4s   = (float*)(ws + 48300032);                     //  3,444,736 B

    k0_pack<<<256, 256, 0, stream>>>(x, xrep, xrepT);
    k1_v1<<<2 * (NLOC / 4), 256, 0, stream>>>(xrep, xrepT, sw, cplx);
    k2_v4<<<NLOC4, 256, 0, stream>>>(cplx, vw, v4s);
    k3_dec<<<B64, 256, 0, stream>>>(v4s, dw, db, out);
}

// Round 5
// 277.723 us; speedup vs baseline: 1.2730x; 1.0041x over previous
//
#include <hip/hip_runtime.h>
#include <hip/hip_bf16.h>
#include <stdint.h>

// ---- problem constants ----
#define B64   64
#define DIMS  120
#define NLOC  (DIMS*DIMS)      // 14400 V1 locations
#define V4D   29
#define NLOC4 (V4D*V4D)        // 841 V4 locations

typedef __attribute__((ext_vector_type(8))) short bf16x8;  // 8 bf16 in 4 VGPRs
typedef __attribute__((ext_vector_type(4))) short bf16x4;  // 4 bf16 in 2 VGPRs
typedef __attribute__((ext_vector_type(4))) float f32x4;

__device__ __forceinline__ unsigned short f2bf(float f) {
    unsigned u = __float_as_uint(f);
    u += 0x7fffu + ((u >> 16) & 1u);   // round-to-nearest-even
    return (unsigned short)(u >> 16);
}

// async global->LDS, 16B per lane (DMA; no VALU, no VGPR round-trip)
// CONSTRAINT (empirical, R2/R4 failures vs R0/R3 passes): issue ONLY in
// the kernel prologue, before the first __syncthreads(); never mid-kernel.
__device__ __forceinline__ void gload16(const float* g, float* l) {
    __builtin_amdgcn_global_load_lds(
        (const __attribute__((address_space(1))) unsigned int*)g,
        (__attribute__((address_space(3))) unsigned int*)l, 16, 0, 0);
}

// ------------------------------------------------------------------
// k0: pack x into two bf16 replica tensors with b innermost for coalesced
// MFMA A-fragment loads. Also bias-initializes out[64][2] (block 0) for
// k3's atomic partial-sum readout (overwrite each launch -> idempotent).
//   xrep [r][col][g][b][q]  = x[b][8g+r+q][col]   (rows chunked)
//   xrepT[rc][row][gc][b][q] = x[b][row][8gc+rc+q] (cols chunked)
// ------------------------------------------------------------------
__global__ __launch_bounds__(256) void k0_pack(const float* __restrict__ x,
                                               unsigned short* __restrict__ xrep,
                                               unsigned short* __restrict__ xrepT,
                                               const float* __restrict__ db,
                                               float* __restrict__ out) {
    __shared__ unsigned short tile[16 * 16 * 64];   // [d1][d2][b]
    int blk = blockIdx.x;
    int tid = threadIdx.x;
    if (blk == 0 && tid < 128) out[tid] = db[tid & 1];   // out[b][cls] = bias
    int isT = (blk >= 128) ? 1 : 0;
    int b2 = blk - 128 * isT;
    int g = b2 >> 3;             // chunk index 0..15
    int fb = (b2 & 7) << 4;      // fixed-dim block base
    int bb = tid >> 2, c4 = (tid & 3) << 2;
#pragma unroll 4
    for (int rr = 0; rr < 16; ++rr) {
        int row, col;
        if (!isT) { row = 8 * g + rr; col = fb + c4; }
        else      { row = fb + rr;    col = 8 * g + c4; }
        f32x4 v;
        if (row < 128 && col < 128)
            v = *(const f32x4*)(x + ((size_t)bb * 128 + row) * 128 + col);
        else
            v = (f32x4){0.f, 0.f, 0.f, 0.f};
#pragma unroll
        for (int cc = 0; cc < 4; ++cc) {
            int d1 = isT ? rr : (c4 + cc);
            int d2 = isT ? (c4 + cc) : rr;
            tile[(d1 * 16 + d2) * 64 + bb] = f2bf(v[cc]);
        }
    }
    __syncthreads();
    unsigned short* outp = isT ? xrepT : xrep;
    int b = tid & 63;
#pragma unroll
    for (int it = 0; it < 32; ++it) {
        int u = (it * 256 + tid) >> 6;   // 0..127
        int d1 = u & 15, rq = u >> 4;    // rq = r (or rc), 0..7
        bf16x8 pk;
#pragma unroll
        for (int q = 0; q < 8; ++q)
            pk[q] = (short)tile[(d1 * 16 + rq + q) * 64 + b];
        size_t off = ((((size_t)rq * 128 + (fb + d1)) * 16 + g) * 64 + b) * 8;
        *(bf16x8*)(outp + off) = pk;
    }
}

// ------------------------------------------------------------------
// k1: V1 locally-connected + relu + phase-mean.  (ROUND-3 PROVEN FORM)
// GRID-SPLIT over channels: 7200 blocks; half = blk&1 selects channels
// half*16..half*16+15; blk0 = blk>>1 selects 4 locations (one per wave).
// Every LDS address staged EXACTLY ONCE via global_load_lds DMA in the
// PROLOGUE; single drain barrier; then compute.  LDS: 20736 B stage +
// 5120 B pool = 25856 B -> 6 blocks/CU.
// K = 96 (3 MFMA K-steps), chunk ch = ks*4 + t:
//   ch 0..8 : patch col kw=ch, rows i..i+7   -> xrep  (e = jj*9+ch)
//   ch 9    : row i+8, cols j..j+7           -> xrepT (e = 72+jj)
//   ch 10   : row i+8, col j+8 (jj==0 only)  -> xrepT at gc+1 (e = 80)
//   ch 11   : pad (masked to zero)
// Each block stores the 4-orientation half of each cplx row (8B/lane,
// disjoint halves of each 16B granule; ordered by kernel boundary).
// ------------------------------------------------------------------
__global__ __launch_bounds__(256) void k1_v1(const unsigned short* __restrict__ xrep,
                                             const unsigned short* __restrict__ xrepT,
                                             const float* __restrict__ sw,
                                             unsigned short* __restrict__ cplx) {
    __shared__ __align__(16) float stagef[16 * 324];   // 20736 B: [c16][loc4*81]
    __shared__ float pool2[4 * 64 * 5];                // 5120 B: [w][64][5]

    int tid = threadIdx.x;
    int blk = blockIdx.x;
    int half = blk & 1;                         // channel half: 0 -> c 0..15, 1 -> c 16..31
    int blk0 = blk >> 1;                        // location block 0..3599
    int blk2 = (blk0 & 7) * 450 + (blk0 >> 3);  // XCD band swizzle (3600 = 8*450)
    int loc0 = blk2 * 4;

    int w = tid >> 6, l = tid & 63;

    // ---- stage 16 channels via DMA: wave w stages c16 = 4w..4w+3 (ONCE) ----
#pragma unroll
    for (int cc = 0; cc < 4; ++cc) {
        int c16 = w * 4 + cc;
        int c = half * 16 + c16;
        const float* g = sw + ((size_t)c * NLOC + loc0) * 81;   // 1296B, 16B-aligned
        float* lp = stagef + c16 * 324;
        gload16(g + l * 4, lp + l * 4);                          // bytes 0..1023
        if (l < 17)
            gload16(g + 256 + l * 4, lp + 256 + l * 4);          // bytes 1024..1295
    }

    int loc = loc0 + w;
    int i = loc / DIMS, j = loc - i * DIMS;
    int ln = l & 15, t = l >> 4;
    int r = i & 7, g2 = i >> 3, rc = j & 7, gc = j >> 3;

    // per-lane B read base (slot ln = phase-local channel, location w)
    const float* bb0 = stagef + (size_t)ln * 324 + w * 81;
    // ks=2 per-lane pattern: off/stride in dwords
    int off2 = (t == 0) ? 8 : ((t == 1) ? 72 : 80);
    int strd2 = (t == 0) ? 9 : ((t == 1) ? 1 : 0);
    bool keep0 = (t <= 2);   // jj==0 valid unless t==3
    bool keepR = (t <= 1);   // jj>=1 valid only for t<=1

    f32x4 acc[4];
#pragma unroll
    for (int mt = 0; mt < 4; ++mt)
        acc[mt] = (f32x4){0.f, 0.f, 0.f, 0.f};

    __syncthreads();   // drain DMA (compiler emits vmcnt(0) before barrier)

#pragma unroll
    for (int ks = 0; ks < 3; ++ks) {
        int ch = ks * 4 + t;
        // ---- A fragments (coalesced 16B global loads) ----
        const unsigned short* abase;
        if (ks < 2) {
            int col = j + ch;    // ch <= 7 here
            abase = xrep + (((size_t)r * 128 + col) * 16 + g2) * 512;
        } else {
            const unsigned short* a0 = xrep + (((size_t)r * 128 + (j + 8)) * 16 + g2) * 512;
            int gc2 = gc + ((t >= 2) ? 1 : 0);
            const unsigned short* a1 = xrepT + (((size_t)rc * 128 + (i + 8)) * 16 + gc2) * 512;
            abase = (t == 0) ? a0 : a1;
        }
        bf16x8 a[4];
#pragma unroll
        for (int mt = 0; mt < 4; ++mt)
            a[mt] = *(const bf16x8*)(abase + (size_t)(ln + 16 * mt) * 8);
        // ---- B fragment: 8 ds_read_b32 + f2bf ----
        bf16x8 bfr;
        if (ks < 2) {
#pragma unroll
            for (int jj = 0; jj < 8; ++jj)
                bfr[jj] = (short)f2bf(bb0[ch + jj * 9]);
        } else {
            {
                float v0 = bb0[off2];
                bfr[0] = (short)f2bf(keep0 ? v0 : 0.0f);
            }
            int o = off2;
#pragma unroll
            for (int jj = 1; jj < 8; ++jj) {
                o += strd2;
                float v0 = bb0[o];
                bfr[jj] = (short)f2bf(keepR ? v0 : 0.0f);
            }
        }
        // ---- MFMAs ----
#pragma unroll
        for (int mt = 0; mt < 4; ++mt)
            acc[mt] = __builtin_amdgcn_mfma_f32_16x16x32_bf16(
                a[mt], bfr, acc[mt], 0, 0, 0);
    }

    // ---- epilogue: relu, phase-mean via shfl_xor, pool write ----
    float* pl = pool2 + w * 64 * 5;
#pragma unroll
    for (int mt = 0; mt < 4; ++mt)
#pragma unroll
        for (int reg = 0; reg < 4; ++reg) {
            float v = fmaxf(acc[mt][reg], 0.0f);
            v += __shfl_xor(v, 1, 64);
            v += __shfl_xor(v, 2, 64);
            if ((ln & 3) == 0) {
                int b = 16 * mt + 4 * t + reg;
                int s = ln >> 2;             // local orientation 0..3
                pl[b * 5 + s] = v * 0.25f;
            }
        }
    __syncthreads();   // pool writes visible before read-back

    // ---- pack & store 4 orientations (8B/lane, half-granule) ----
    bf16x4 po;
#pragma unroll
    for (int s = 0; s < 4; ++s)
        po[s] = (short)f2bf(pl[l * 5 + s]);
    *(bf16x4*)(cplx + (size_t)loc * 512 + l * 8 + half * 4) = po;
}

// ------------------------------------------------------------------
// k2: V4 pooling. One block per location; vw slice staged RAW fp32 via
// global_load_lds DMA (prologue-only): row ro=o*8+s (256B, 256B-aligned)
// -> LDS base (s*16+o)*68 dwords (272B stride: 16B-aligned bases, 2-way
// banks). B-frag read-side: 8 ds_read_b32 (imm offset s*4352B) + f2bf.
// 4 waves split K, LDS reduce across waves.
// ------------------------------------------------------------------
__global__ __launch_bounds__(256) void k2_v4(const unsigned short* __restrict__ cplx,
                                             const float* __restrict__ vw,
                                             float* __restrict__ v4s) {
    __shared__ __align__(16) char smraw[128 * 68 * 4];   // 34816 B
    float* stg = (float*)smraw;                          // [s*16+o][68] fp32
    float* pool = (float*)smraw;                         // [4][64][16] fp32 (overlay)

    int tid = threadIdx.x;
    int blk = blockIdx.x;
    int loc = (blk < 840) ? ((blk & 7) * 105 + (blk >> 3)) : 840;  // XCD band swizzle
    int oi = loc / V4D, oj = loc - oi * V4D;

    int w = tid >> 6, l = tid & 63;

    // ---- stage vw[.,.,loc,.] via DMA: wave w rows ro = 32w..32w+31 ----
    if (l < 16) {
#pragma unroll
        for (int m = 0; m < 32; ++m) {
            int ro = w * 32 + m;
            int o = ro >> 3, s = ro & 7;
            const float* g = vw + ((size_t)ro * NLOC4 + loc) * 64;   // 256B aligned
            float* lp = stg + (s * 16 + o) * 68;
            gload16(g + l * 4, lp + l * 4);
        }
    }

    int ln = l & 15, t = l >> 4;
    f32x4 acc[4];
#pragma unroll
    for (int mt = 0; mt < 4; ++mt) acc[mt] = (f32x4){0.f, 0.f, 0.f, 0.f};

    __syncthreads();   // drain DMA

    const float* brow = stg + ln * 68;
#pragma unroll
    for (int kk = 0; kk < 4; ++kk) {
        int pos = 4 * (w * 4 + kk) + t;      // 0..63
        int kh = pos >> 3, kw = pos & 7;
        int iloc = (oi * 4 + kh) * DIMS + oj * 4 + kw;
        const unsigned short* ab = cplx + (size_t)iloc * 512 + ln * 8;
        bf16x8 a[4];
#pragma unroll
        for (int mt = 0; mt < 4; ++mt)
            a[mt] = *(const bf16x8*)(ab + mt * 128);
        bf16x8 bb;
#pragma unroll
        for (int s = 0; s < 8; ++s)
            bb[s] = (short)f2bf(brow[s * 16 * 68 + pos]);
#pragma unroll
        for (int mt = 0; mt < 4; ++mt)
            acc[mt] = __builtin_amdgcn_mfma_f32_16x16x32_bf16(a[mt], bb, acc[mt], 0, 0, 0);
    }
    __syncthreads();                       // stg dead; pool overlays
#pragma unroll
    for (int mt = 0; mt < 4; ++mt)
#pragma unroll
        for (int reg = 0; reg < 4; ++reg)
            pool[((w * 64) + 16 * mt + 4 * t + reg) * 16 + ln] = acc[mt][reg];
    __syncthreads();
    int o = tid & 15, brw = tid >> 4;
#pragma unroll
    for (int itb = 0; itb < 4; ++itb) {
        int b = brw + 16 * itb;
        float s = pool[(0 * 64 + b) * 16 + o] + pool[(1 * 64 + b) * 16 + o] +
                  pool[(2 * 64 + b) * 16 + o] + pool[(3 * 64 + b) * 16 + o];
        v4s[(size_t)loc * 1024 + b * 16 + o] = s;
    }
}

// ------------------------------------------------------------------
// k3: decision readout. 256 blocks = 4 location-parts per batch element;
// partial sums accumulated into bias-pre-initialized out via 2 atomicAdds
// per block (512 total over 128 addresses -> negligible contention).
// ------------------------------------------------------------------
__global__ __launch_bounds__(256) void k3_dec(const float* __restrict__ v4s,
                                              const float* __restrict__ dw,
                                              float* __restrict__ out) {
    int blk = blockIdx.x, tid = threadIdx.x;
    int b = blk >> 2, part = blk & 3;
    int start = part * 210;
    int lim = start + ((part == 3) ? 211 : 210);
    int loc = start + tid;
    float a0 = 0.f, a1 = 0.f;
    if (loc < lim) {
        const float* vp = v4s + (size_t)loc * 1024 + b * 16;
#pragma unroll
        for (int o4 = 0; o4 < 4; ++o4) {
            f32x4 v = *(const f32x4*)(vp + o4 * 4);
#pragma unroll
            for (int q = 0; q < 4; ++q) {
                int o = o4 * 4 + q;
                a0 += v[q] * dw[o * NLOC4 + loc];
                a1 += v[q] * dw[16 * NLOC4 + o * NLOC4 + loc];
            }
        }
    }
    __shared__ float r0[256], r1[256];
    r0[tid] = a0; r1[tid] = a1;
    __syncthreads();
    for (int s = 128; s > 0; s >>= 1) {
        if (tid < s) { r0[tid] += r0[tid + s]; r1[tid] += r1[tid + s]; }
        __syncthreads();
    }
    if (tid == 0) {
        atomicAdd(out + 2 * b + 0, r0[0]);
        atomicAdd(out + 2 * b + 1, r1[0]);
    }
}

// ------------------------------------------------------------------
extern "C" void kernel_launch(void* const* d_in, const int* in_sizes, int n_in,
                              void* d_out, int out_size, void* d_ws, size_t ws_size,
                              hipStream_t stream) {
    const float* x  = (const float*)d_in[0];   // [64][1][128][128]
    const float* sw = (const float*)d_in[1];   // [32][120][120][81]
    const float* vw = (const float*)d_in[2];   // [16][8][29][29][64]
    const float* dw = (const float*)d_in[3];   // [2][13456]
    const float* db = (const float*)d_in[4];   // [2]
    float* out = (float*)d_out;                // [64][2]

    char* ws = (char*)d_ws;
    unsigned short* xrep  = (unsigned short*)ws;                         // 16,777,216 B
    unsigned short* xrepT = (unsigned short*)(ws + 16777216);            // 16,777,216 B
    unsigned short* cplx  = (unsigned short*)(ws + 33554432);            // 14,745,600 B
    float*          v4s   = (float*)(ws + 48300032);                     //  3,444,736 B

    k0_pack<<<256, 256, 0, stream>>>(x, xrep, xrepT, db, out);
    k1_v1<<<2 * (NLOC / 4), 256, 0, stream>>>(xrep, xrepT, sw, cplx);
    k2_v4<<<NLOC4, 256, 0, stream>>>(cplx, vw, v4s);
    k3_dec<<<4 * B64, 256, 0, stream>>>(v4s, dw, out);
}

// Round 6
// 273.018 us; speedup vs baseline: 1.2949x; 1.0172x over previous
//
#include <hip/hip_runtime.h>
#include <hip/hip_bf16.h>
#include <stdint.h>

// ---- problem constants ----
#define B64   64
#define DIMS  120
#define NLOC  (DIMS*DIMS)      // 14400 V1 locations
#define V4D   29
#define NLOC4 (V4D*V4D)        // 841 V4 locations

typedef __attribute__((ext_vector_type(8))) short bf16x8;  // 8 bf16 in 4 VGPRs
typedef __attribute__((ext_vector_type(4))) float f32x4;

__device__ __forceinline__ unsigned short f2bf(float f) {
    unsigned u = __float_as_uint(f);
    u += 0x7fffu + ((u >> 16) & 1u);   // round-to-nearest-even
    return (unsigned short)(u >> 16);
}

// async global->LDS DMA. CONSTRAINTS (empirical R2/R4 fails vs R0/R3/R5
// passes): (1) issue ONLY in the kernel prologue before the first
// __syncthreads(); (2) active-lane mask must start at lane 0 and be
// contiguous (dest = wave-uniform base + lane*size).
__device__ __forceinline__ void gload16(const float* g, float* l) {
    __builtin_amdgcn_global_load_lds(
        (const __attribute__((address_space(1))) unsigned int*)g,
        (__attribute__((address_space(3))) unsigned int*)l, 16, 0, 0);
}
__device__ __forceinline__ void gload4(const float* g, float* l) {
    __builtin_amdgcn_global_load_lds(
        (const __attribute__((address_space(1))) unsigned int*)g,
        (__attribute__((address_space(3))) unsigned int*)l, 4, 0, 0);
}

// ------------------------------------------------------------------
// k0: pack x into two bf16 replica tensors with b innermost for coalesced
// MFMA A-fragment loads. Also bias-initializes out[64][2] (block 0) for
// k3's atomic partial-sum readout (overwrite each launch -> idempotent).
//   xrep [r][col][g][b][q]  = x[b][8g+r+q][col]   (rows chunked)
//   xrepT[rc][row][gc][b][q] = x[b][row][8gc+rc+q] (cols chunked)
// ------------------------------------------------------------------
__global__ __launch_bounds__(256) void k0_pack(const float* __restrict__ x,
                                               unsigned short* __restrict__ xrep,
                                               unsigned short* __restrict__ xrepT,
                                               const float* __restrict__ db,
                                               float* __restrict__ out) {
    __shared__ unsigned short tile[16 * 16 * 64];   // [d1][d2][b]
    int blk = blockIdx.x;
    int tid = threadIdx.x;
    if (blk == 0 && tid < 128) out[tid] = db[tid & 1];   // out[b][cls] = bias
    int isT = (blk >= 128) ? 1 : 0;
    int b2 = blk - 128 * isT;
    int g = b2 >> 3;             // chunk index 0..15
    int fb = (b2 & 7) << 4;      // fixed-dim block base
    int bb = tid >> 2, c4 = (tid & 3) << 2;
#pragma unroll 4
    for (int rr = 0; rr < 16; ++rr) {
        int row, col;
        if (!isT) { row = 8 * g + rr; col = fb + c4; }
        else      { row = fb + rr;    col = 8 * g + c4; }
        f32x4 v;
        if (row < 128 && col < 128)
            v = *(const f32x4*)(x + ((size_t)bb * 128 + row) * 128 + col);
        else
            v = (f32x4){0.f, 0.f, 0.f, 0.f};
#pragma unroll
        for (int cc = 0; cc < 4; ++cc) {
            int d1 = isT ? rr : (c4 + cc);
            int d2 = isT ? (c4 + cc) : rr;
            tile[(d1 * 16 + d2) * 64 + bb] = f2bf(v[cc]);
        }
    }
    __syncthreads();
    unsigned short* outp = isT ? xrepT : xrep;
    int b = tid & 63;
#pragma unroll
    for (int it = 0; it < 32; ++it) {
        int u = (it * 256 + tid) >> 6;   // 0..127
        int d1 = u & 15, rq = u >> 4;    // rq = r (or rc), 0..7
        bf16x8 pk;
#pragma unroll
        for (int q = 0; q < 8; ++q)
            pk[q] = (short)tile[(d1 * 16 + rq + q) * 64 + b];
        size_t off = ((((size_t)rq * 128 + (fb + d1)) * 16 + g) * 64 + b) * 8;
        *(bf16x8*)(outp + off) = pk;
    }
}

// ------------------------------------------------------------------
// k1: V1 locally-connected + relu + phase-mean.  ONE WAVE PER BLOCK.
// Block = 64 threads = 1 wave = 1 location x ALL 32 channels.
//  - eliminates the cross-wave DMA convoy entirely (stage/drain is
//    wave-local); 12 independent single-wave blocks per CU, each with
//    its own 10.75 KB DMA stream in flight.
//  - halves A-fragment replica traffic vs the half-split form (each
//    location's xrep/xrepT fragments read once, not twice).
// Staging: 32 rows x 84 dwords (336 B, 16B-aligned, +3 pad dwords);
// one 21-lane gload16 per channel (g + l*4 dwords, lanes 0..20).
// Pad dwords read 12 B past sw[c][loc] end -- harmless except the very
// last (c=31, loc=14399), which is special-cased (20 lanes + lane-0
// gload4 of dword 80). Prologue-only DMA + A-preload -> one
// __syncthreads drain -> pure LDS+MFMA compute (R0-proven 32-channel
// index math: 2 n-tiles, 24 MFMAs, pool[64][9], full bf16x8 store).
// LDS 13056 B -> 12 blocks/CU (launch_bounds (64,3): 3 waves/EU).
// ------------------------------------------------------------------
__global__ __launch_bounds__(64, 3) void k1_v1(const unsigned short* __restrict__ xrep,
                                               const unsigned short* __restrict__ xrepT,
                                               const float* __restrict__ sw,
                                               unsigned short* __restrict__ cplx) {
    __shared__ __align__(16) float stg[32 * 84];   // 10752 B: [c][84]
    __shared__ float pool[64 * 9];                 // 2304 B: [b][9]

    int l = threadIdx.x;
    int blk = blockIdx.x;
    int loc = (blk & 7) * 1800 + (blk >> 3);       // XCD band swizzle (14400 = 8*1800)
    int i = loc / DIMS, j = loc - i * DIMS;

    // ---- stage 32 channels x 81 dwords via DMA (prologue only) ----
    bool lastLoc = (loc == NLOC - 1);
#pragma unroll
    for (int c = 0; c < 32; ++c) {
        const float* g = sw + ((size_t)c * NLOC + loc) * 81;   // 324 B
        float* lp = stg + c * 84;
        int nl = (c == 31) ? (lastLoc ? 20 : 21) : 21;
        if (l < nl) gload16(g + l * 4, lp + l * 4);
    }
    if (lastLoc && l == 0)
        gload4(sw + ((size_t)31 * NLOC + loc) * 81 + 80, stg + 31 * 84 + 80);

    int ln = l & 15, t = l >> 4;
    int r = i & 7, g2 = i >> 3, rc = j & 7, gc = j >> 3;

    // ---- preload A fragments (regular VGPR loads, still prologue) ----
    bf16x8 a[3][4];
#pragma unroll
    for (int ks = 0; ks < 3; ++ks) {
        const unsigned short* abase;
        if (ks < 2) {
            int col = j + ks * 4 + t;    // ch <= 7 here
            abase = xrep + (((size_t)r * 128 + col) * 16 + g2) * 512;
        } else {
            const unsigned short* a0 = xrep + (((size_t)r * 128 + (j + 8)) * 16 + g2) * 512;
            int gc2 = gc + ((t >= 2) ? 1 : 0);
            const unsigned short* a1 = xrepT + (((size_t)rc * 128 + (i + 8)) * 16 + gc2) * 512;
            abase = (t == 0) ? a0 : a1;
        }
#pragma unroll
        for (int mt = 0; mt < 4; ++mt)
            a[ks][mt] = *(const bf16x8*)(abase + (size_t)(ln + 16 * mt) * 8);
    }

    // per-lane B read bases (two n-tiles), fp32 rows of 84 dwords
    const float* bb0 = stg + (size_t)ln * 84;
    const float* bb1 = stg + (size_t)(16 + ln) * 84;
    // ks=2 per-lane pattern: off/stride in dwords
    int off2 = (t == 0) ? 8 : ((t == 1) ? 72 : 80);
    int strd2 = (t == 0) ? 9 : ((t == 1) ? 1 : 0);
    bool keep0 = (t <= 2);   // jj==0 valid unless t==3
    bool keepR = (t <= 1);   // jj>=1 valid only for t<=1

    f32x4 acc[4][2];
#pragma unroll
    for (int mt = 0; mt < 4; ++mt)
#pragma unroll
        for (int nt = 0; nt < 2; ++nt)
            acc[mt][nt] = (f32x4){0.f, 0.f, 0.f, 0.f};

    __syncthreads();   // drain DMA (vmcnt0 before barrier); wave-local

#pragma unroll
    for (int ks = 0; ks < 3; ++ks) {
        int ch = ks * 4 + t;
        // ---- B fragments: 8 ds_read_b32 + f2bf each ----
        bf16x8 bfr[2];
        if (ks < 2) {
#pragma unroll
            for (int jj = 0; jj < 8; ++jj) {
                bfr[0][jj] = (short)f2bf(bb0[ch + jj * 9]);
                bfr[1][jj] = (short)f2bf(bb1[ch + jj * 9]);
            }
        } else {
            {
                float v0 = bb0[off2], v1 = bb1[off2];
                bfr[0][0] = (short)f2bf(keep0 ? v0 : 0.0f);
                bfr[1][0] = (short)f2bf(keep0 ? v1 : 0.0f);
            }
            int o = off2;
#pragma unroll
            for (int jj = 1; jj < 8; ++jj) {
                o += strd2;
                float v0 = bb0[o], v1 = bb1[o];
                bfr[0][jj] = (short)f2bf(keepR ? v0 : 0.0f);
                bfr[1][jj] = (short)f2bf(keepR ? v1 : 0.0f);
            }
        }
        // ---- MFMAs ----
#pragma unroll
        for (int mt = 0; mt < 4; ++mt)
#pragma unroll
            for (int nt = 0; nt < 2; ++nt)
                acc[mt][nt] = __builtin_amdgcn_mfma_f32_16x16x32_bf16(
                    a[ks][mt], bfr[nt], acc[mt][nt], 0, 0, 0);
    }

    // ---- epilogue: relu, phase-mean via shfl_xor, pool transpose ----
#pragma unroll
    for (int mt = 0; mt < 4; ++mt)
#pragma unroll
        for (int nt = 0; nt < 2; ++nt)
#pragma unroll
            for (int reg = 0; reg < 4; ++reg) {
                float v = fmaxf(acc[mt][nt][reg], 0.0f);
                v += __shfl_xor(v, 1, 64);
                v += __shfl_xor(v, 2, 64);
                if ((ln & 3) == 0) {
                    int b = 16 * mt + 4 * t + reg;
                    int s = 4 * nt + (ln >> 2);
                    pool[b * 9 + s] = v * 0.25f;
                }
            }
    __syncthreads();   // pool writes visible (wave-local lgkm drain)

    bf16x8 po;
#pragma unroll
    for (int s = 0; s < 8; ++s)
        po[s] = (short)f2bf(pool[l * 9 + s]);
    *(bf16x8*)(cplx + (size_t)loc * 512 + l * 8) = po;
}

// ------------------------------------------------------------------
// k2: V4 pooling. One block per location; vw slice staged RAW fp32 via
// global_load_lds DMA (prologue-only): row ro=o*8+s (256B, 256B-aligned)
// -> LDS base (s*16+o)*68 dwords (272B stride: 16B-aligned bases, 2-way
// banks). B-frag read-side: 8 ds_read_b32 (imm offset s*4352B) + f2bf.
// 4 waves split K, LDS reduce across waves.
// ------------------------------------------------------------------
__global__ __launch_bounds__(256) void k2_v4(const unsigned short* __restrict__ cplx,
                                             const float* __restrict__ vw,
                                             float* __restrict__ v4s) {
    __shared__ __align__(16) char smraw[128 * 68 * 4];   // 34816 B
    float* stg = (float*)smraw;                          // [s*16+o][68] fp32
    float* pool = (float*)smraw;                         // [4][64][16] fp32 (overlay)

    int tid = threadIdx.x;
    int blk = blockIdx.x;
    int loc = (blk < 840) ? ((blk & 7) * 105 + (blk >> 3)) : 840;  // XCD band swizzle
    int oi = loc / V4D, oj = loc - oi * V4D;

    int w = tid >> 6, l = tid & 63;

    // ---- stage vw[.,.,loc,.] via DMA: wave w rows ro = 32w..32w+31 ----
    if (l < 16) {
#pragma unroll
        for (int m = 0; m < 32; ++m) {
            int ro = w * 32 + m;
            int o = ro >> 3, s = ro & 7;
            const float* g = vw + ((size_t)ro * NLOC4 + loc) * 64;   // 256B aligned
            float* lp = stg + (s * 16 + o) * 68;
            gload16(g + l * 4, lp + l * 4);
        }
    }

    int ln = l & 15, t = l >> 4;
    f32x4 acc[4];
#pragma unroll
    for (int mt = 0; mt < 4; ++mt) acc[mt] = (f32x4){0.f, 0.f, 0.f, 0.f};

    __syncthreads();   // drain DMA

    const float* brow = stg + ln * 68;
#pragma unroll
    for (int kk = 0; kk < 4; ++kk) {
        int pos = 4 * (w * 4 + kk) + t;      // 0..63
        int kh = pos >> 3, kw = pos & 7;
        int iloc = (oi * 4 + kh) * DIMS + oj * 4 + kw;
        const unsigned short* ab = cplx + (size_t)iloc * 512 + ln * 8;
        bf16x8 a[4];
#pragma unroll
        for (int mt = 0; mt < 4; ++mt)
            a[mt] = *(const bf16x8*)(ab + mt * 128);
        bf16x8 bb;
#pragma unroll
        for (int s = 0; s < 8; ++s)
            bb[s] = (short)f2bf(brow[s * 16 * 68 + pos]);
#pragma unroll
        for (int mt = 0; mt < 4; ++mt)
            acc[mt] = __builtin_amdgcn_mfma_f32_16x16x32_bf16(a[mt], bb, acc[mt], 0, 0, 0);
    }
    __syncthreads();                       // stg dead; pool overlays
#pragma unroll
    for (int mt = 0; mt < 4; ++mt)
#pragma unroll
        for (int reg = 0; reg < 4; ++reg)
            pool[((w * 64) + 16 * mt + 4 * t + reg) * 16 + ln] = acc[mt][reg];
    __syncthreads();
    int o = tid & 15, brw = tid >> 4;
#pragma unroll
    for (int itb = 0; itb < 4; ++itb) {
        int b = brw + 16 * itb;
        float s = pool[(0 * 64 + b) * 16 + o] + pool[(1 * 64 + b) * 16 + o] +
                  pool[(2 * 64 + b) * 16 + o] + pool[(3 * 64 + b) * 16 + o];
        v4s[(size_t)loc * 1024 + b * 16 + o] = s;
    }
}

// ------------------------------------------------------------------
// k3: decision readout. 256 blocks = 4 location-parts per batch element;
// partial sums accumulated into bias-pre-initialized out via 2 atomicAdds
// per block (512 total over 128 addresses -> negligible contention).
// ------------------------------------------------------------------
__global__ __launch_bounds__(256) void k3_dec(const float* __restrict__ v4s,
                                              const float* __restrict__ dw,
                                              float* __restrict__ out) {
    int blk = blockIdx.x, tid = threadIdx.x;
    int b = blk >> 2, part = blk & 3;
    int start = part * 210;
    int lim = start + ((part == 3) ? 211 : 210);
    int loc = start + tid;
    float a0 = 0.f, a1 = 0.f;
    if (loc < lim) {
        const float* vp = v4s + (size_t)loc * 1024 + b * 16;
#pragma unroll
        for (int o4 = 0; o4 < 4; ++o4) {
            f32x4 v = *(const f32x4*)(vp + o4 * 4);
#pragma unroll
            for (int q = 0; q < 4; ++q) {
                int o = o4 * 4 + q;
                a0 += v[q] * dw[o * NLOC4 + loc];
                a1 += v[q] * dw[16 * NLOC4 + o * NLOC4 + loc];
            }
        }
    }
    __shared__ float r0[256], r1[256];
    r0[tid] = a0; r1[tid] = a1;
    __syncthreads();
    for (int s = 128; s > 0; s >>= 1) {
        if (tid < s) { r0[tid] += r0[tid + s]; r1[tid] += r1[tid + s]; }
        __syncthreads();
    }
    if (tid == 0) {
        atomicAdd(out + 2 * b + 0, r0[0]);
        atomicAdd(out + 2 * b + 1, r1[0]);
    }
}

// ------------------------------------------------------------------
extern "C" void kernel_launch(void* const* d_in, const int* in_sizes, int n_in,
                              void* d_out, int out_size, void* d_ws, size_t ws_size,
                              hipStream_t stream) {
    const float* x  = (const float*)d_in[0];   // [64][1][128][128]
    const float* sw = (const float*)d_in[1];   // [32][120][120][81]
    const float* vw = (const float*)d_in[2];   // [16][8][29][29][64]
    const float* dw = (const float*)d_in[3];   // [2][13456]
    const float* db = (const float*)d_in[4];   // [2]
    float* out = (float*)d_out;                // [64][2]

    char* ws = (char*)d_ws;
    unsigned short* xrep  = (unsigned short*)ws;                         // 16,777,216 B
    unsigned short* xrepT = (unsigned short*)(ws + 16777216);            // 16,777,216 B
    unsigned short* cplx  = (unsigned short*)(ws + 33554432);            // 14,745,600 B
    float*          v4s   = (float*)(ws + 48300032);                     //  3,444,736 B

    k0_pack<<<256, 256, 0, stream>>>(x, xrep, xrepT, db, out);
    k1_v1<<<NLOC, 64, 0, stream>>>(xrep, xrepT, sw, cplx);
    k2_v4<<<NLOC4, 256, 0, stream>>>(cplx, vw, v4s);
    k3_dec<<<4 * B64, 256, 0, stream>>>(v4s, dw, out);
}